// Round 12
// baseline (50.923 us; speedup 1.0000x reference)
//
#include <hip/hip_runtime.h>
#include <hip/hip_bf16.h>
#include <stdint.h>

typedef __attribute__((ext_vector_type(8))) short bf16x8;
typedef __attribute__((ext_vector_type(4))) float f32x4;
typedef __attribute__((ext_vector_type(16))) float f32x16;

#define MFMA32(a, b, c) __builtin_amdgcn_mfma_f32_32x32x16_bf16((a), (b), (c), 0, 0, 0)

__device__ __forceinline__ unsigned short f2bf_rn(float f) {
    union { __bf16 b; unsigned short u; } v;
    v.b = (__bf16)f;
    return v.u;
}

// pack 2 floats -> 2 bf16 in a uint (compiler fuses to v_cvt_pk_bf16_f32)
__device__ __forceinline__ unsigned int pk2(float lo, float hi) {
    union { unsigned short s[2]; unsigned int u; } r;
    r.s[0] = f2bf_rn(lo); r.s[1] = f2bf_rn(hi);
    return r.u;
}

__device__ __forceinline__ void gload_lds16(const void* g, void* l) {
    __builtin_amdgcn_global_load_lds(
        (const __attribute__((address_space(1))) void*)g,
        (__attribute__((address_space(3))) void*)l, 16, 0, 0);
}

// ---------------------------------------------------------------------------
// prep_h: transpose each 128x128 fp32 block of the 8 H tensors to bf16.
//   ht[j][blk][k][r] = h_j[blk][r][k]
// 256 WGs = jblk(64) x k-quarter(4).
// ---------------------------------------------------------------------------
__global__ __launch_bounds__(256) void prep_h(
    const float* __restrict__ h0, const float* __restrict__ h1,
    const float* __restrict__ h2, const float* __restrict__ h3,
    const float* __restrict__ h4, const float* __restrict__ h5,
    const float* __restrict__ h6, const float* __restrict__ h7,
    unsigned short* __restrict__ ht)
{
    const float* hmap[8] = {h0, h1, h2, h3, h4, h5, h6, h7};
    const int wg = blockIdx.x;            // 256 = jblk(64) x quarter(4)
    const int jblk = wg >> 2, qt = wg & 3;
    const float* src = hmap[jblk >> 3] + (jblk & 7) * 16384;
    unsigned short* dst = ht + jblk * 16384;
    __shared__ unsigned short tile[32 * 129];
    const int t = threadIdx.x;
    #pragma unroll
    for (int i = 0; i < 16; ++i) {
        int idx = t + 256 * i;            // 4096 = r(128) x kk(32)
        int r = idx >> 5, kk = idx & 31;
        tile[kk * 129 + r] = f2bf_rn(src[r * 128 + qt * 32 + kk]);
    }
    __syncthreads();
    #pragma unroll
    for (int i = 0; i < 16; ++i) {
        int idx = t + 256 * i;            // 4096 = k(32) x r(128)
        int k = idx >> 7, r = idx & 127;
        dst[(qt * 32 + k) * 128 + r] = tile[k * 129 + r];
    }
}

// ---------------------------------------------------------------------------
// bilin_main: 256 WGs = (b,p,q), q = bid&7 (XCD-locked). 256 threads =
// 4 waves, wave wn owns output cols wn*32..+32, full K=128. 32x32x16 MFMA.
// SOFTWARE-PIPELINED c-loop (R11 was latency-bound at MfmaUtil 16%,
// 1 wave/SIMD): phase cc overlaps stage B(cc) with stage A(cc+1) —
// independent dependency trees (Lt/u vs W/xf) interleaved in one basic
// block, ONE barrier per phase.  u-slot reuse: B t0-3 consumes u[0..1],
// then A(cc+1) m2=0,1 refills u[0..1]; B t4-7 consumes u[2..3], then
// A m2=2,3 refills.  W and Lt double-buffered: at top of cc issue
// W(cc+2)->W[cc&1] (A(cc) read it in cc-1) and Lt(cc+1)->Lt[~cc&1]
// (B(cc-1) read it in cc-1); both drain at the barrier entering cc+1.
// X: one 32KB plane; xre staged+loaded in prologue, then xim overwrites
// the plane (reads hit L3); xf(im) reloaded from LDS at top of cc=3.
// LDS = X 32K + W 2x32K + Lt 2x32K = 160 KB exact.
// Registers: y 128 + xf 128 + u 64 + wfc 32 ~= 400 peak (<450 no-spill).
// LDS swizzle: 16B chunk ch of row at LDS[row][ch] = G[row][ch ^ (row&15)].
// ---------------------------------------------------------------------------
__global__ __launch_bounds__(256, 1) void bilin_main(
    const float* __restrict__ x, const int* __restrict__ perm,
    const unsigned short* __restrict__ ht, float* __restrict__ out)
{
    const int wg = blockIdx.x;
    const int q = wg & 7, p = (wg >> 3) & 7, b = wg >> 6;
    const int tid = threadIdx.x;
    const int lane = tid & 63, wn = tid >> 6;      // 4 waves
    const int l31 = lane & 31, hl = lane >> 5;

    __shared__ __align__(16) unsigned short smem[81920];   // 160 KB
    unsigned short* xplane = smem;                         // 32 KB
    // W[par]  = smem + 16384 + par*16384   (64 KB)
    // Lt[par] = smem + 49152 + par*16384   (64 KB)

    constexpr int cseq[8]  = {0, 1, 6, 7, 2, 3, 4, 5};
    constexpr int rperm[8] = {0, 1, 3, 2, 4, 5, 7, 6};

    // ---- staging helpers (gload_lds: wave-uniform LDS base + lane*16) ----
    const int wubase = tid & ~63;
    auto stage_h = [&](unsigned short* dst, int blk) {
        const unsigned short* src = ht + blk * 16384;
        #pragma unroll
        for (int r = 0; r < 8; ++r) {
            const int idx = r * 256 + tid;          // 16B chunk 0..2047
            const int row = idx >> 4, cin = idx & 15;
            gload_lds16(src + row * 128 + ((cin ^ (row & 15)) << 3),
                        dst + ((r * 256 + wubase) << 3));
        }
    };

    // swizzled LDS fragment read: row in [0,128), chunk in [0,16)
    auto ldr = [&](const unsigned short* base, int row, int ch) -> bf16x8 {
        return *(const bf16x8*)(base + row * 128 + ((ch ^ (row & 15)) << 3));
    };

    // fused prep_x: fp32 read (perm in address) -> convert -> swizzled plane
    auto stage_x = [&](int g) {
        #pragma unroll
        for (int i = 0; i < 8; ++i) {
            const int idx = i * 256 + tid;
            const int row = idx >> 4, cin = idx & 15;
            const int n1 = perm[2 * p + (row >> 6)];
            const int n2 = perm[2 * q + (cin >> 3)];
            const int r1 = row & 63, r2 = (cin & 7) * 8;
            const float* sp = x + ((size_t)((b * 16 + n1) * 64 + r1) * 1024
                                   + n2 * 64 + r2) * 2;
            float4 v0 = *(const float4*)(sp);
            float4 v1 = *(const float4*)(sp + 4);
            float4 v2 = *(const float4*)(sp + 8);
            float4 v3 = *(const float4*)(sp + 12);
            bf16x8 t;
            if (g == 0) {
                t[0] = (short)f2bf_rn(v0.x); t[1] = (short)f2bf_rn(v0.z);
                t[2] = (short)f2bf_rn(v1.x); t[3] = (short)f2bf_rn(v1.z);
                t[4] = (short)f2bf_rn(v2.x); t[5] = (short)f2bf_rn(v2.z);
                t[6] = (short)f2bf_rn(v3.x); t[7] = (short)f2bf_rn(v3.z);
            } else {
                t[0] = (short)f2bf_rn(v0.y); t[1] = (short)f2bf_rn(v0.w);
                t[2] = (short)f2bf_rn(v1.y); t[3] = (short)f2bf_rn(v1.w);
                t[4] = (short)f2bf_rn(v2.y); t[5] = (short)f2bf_rn(v2.w);
                t[6] = (short)f2bf_rn(v3.y); t[7] = (short)f2bf_rn(v3.w);
            }
            *(bf16x8*)(xplane + row * 128 + ((cin ^ (row & 15)) << 3)) = t;
        }
    };

    // X fragments (whole 128-row tile, one plane) in registers: 128 VGPRs
    bf16x8 xf[4][8];
    auto load_xf = [&]() {
        #pragma unroll
        for (int m2 = 0; m2 < 4; ++m2)
            #pragma unroll
            for (int ks = 0; ks < 8; ++ks)
                xf[m2][ks] = ldr(xplane, m2 * 32 + l31, 2 * ks + hl);
    };

    // ---- prologue ----
    stage_h(smem + 16384, rperm[cseq[0]] * 8 + q);   // W(0) -> W[0]
    stage_h(smem + 32768, rperm[cseq[1]] * 8 + q);   // W(1) -> W[1]
    stage_h(smem + 49152, cseq[0] * 8 + p);          // Lt(0) -> Lt[0]
    stage_x(0);                                      // xre plane
    __syncthreads();     // drains W(0),W(1),Lt(0),xre
    load_xf();           // xf = Xre
    __syncthreads();     // all waves done reading the plane

    f32x16 yre[4], yim[4], u[4];
    #pragma unroll
    for (int i = 0; i < 4; ++i)
        #pragma unroll
        for (int e = 0; e < 16; ++e) { yre[i][e] = 0.f; yim[i][e] = 0.f; }

    // A(0): u[m2] = Xre . W_c0, full K=128
    {
        const unsigned short* wb = smem + 16384;
        #pragma unroll
        for (int m2 = 0; m2 < 4; ++m2)
            #pragma unroll
            for (int e = 0; e < 16; ++e) u[m2][e] = 0.f;
        #pragma unroll
        for (int ks = 0; ks < 8; ++ks) {
            bf16x8 wfr = ldr(wb, wn * 32 + l31, 2 * ks + hl);
            #pragma unroll
            for (int m2 = 0; m2 < 4; ++m2)
                u[m2] = MFMA32(xf[m2][ks], wfr, u[m2]);
        }
    }
    stage_x(1);          // overwrite plane with Xim (reads hit L3); each
                         // wave's writes complete before its next barrier

    // B(t) for c-term cc: consumes u[t>>1], accumulates into yre/yim
    auto BT = [&](int t, const unsigned short* lb, bool isRe) {
        const int f = t >> 1, qa = (t & 1) * 2, qb = qa + 1;
        unsigned int lo0 = pk2(u[f][4 * qa + 0], u[f][4 * qa + 1]);
        unsigned int lo1 = pk2(u[f][4 * qa + 2], u[f][4 * qa + 3]);
        unsigned int hi0 = pk2(u[f][4 * qb + 0], u[f][4 * qb + 1]);
        unsigned int hi1 = pk2(u[f][4 * qb + 2], u[f][4 * qb + 3]);
        unsigned int send0 = hl ? lo0 : hi0;
        unsigned int send1 = hl ? lo1 : hi1;
        unsigned int sx0 = (unsigned int)__shfl_xor((int)send0, 32);
        unsigned int sx1 = (unsigned int)__shfl_xor((int)send1, 32);
        union { unsigned int d[4]; bf16x8 v; } ufu;
        ufu.d[0] = hl ? sx0 : lo0;
        ufu.d[1] = hl ? sx1 : lo1;
        ufu.d[2] = hl ? hi0 : sx0;
        ufu.d[3] = hl ? hi1 : sx1;
        #pragma unroll
        for (int mt = 0; mt < 4; ++mt) {
            bf16x8 lfr = ldr(lb, mt * 32 + l31, 2 * t + hl);
            if (isRe) yre[mt] = MFMA32(lfr, ufu.v, yre[mt]);
            else      yim[mt] = MFMA32(lfr, ufu.v, yim[mt]);
        }
    };

    #pragma unroll
    for (int cc = 0; cc < 8; ++cc) {
        __syncthreads();   // entering cc: drains W(cc+1) [used by A(cc+1)
                           // this phase] and Lt(cc) [used by B(cc)]

        // issue future stages: W(cc+2) -> W[cc&1] (A(cc) read it in cc-1),
        // Lt(cc+1) -> Lt[(cc+1)&1] (B(cc-1) read it in cc-1)
        if (cc < 6)
            stage_h(smem + 16384 + (cc & 1) * 16384,
                    rperm[cseq[cc + 2]] * 8 + q);
        if (cc < 7)
            stage_h(smem + 49152 + ((cc + 1) & 1) * 16384,
                    cseq[cc + 1] * 8 + p);

        // g switch: A(4) (computed this phase) needs Xim fragments
        if (cc == 3) load_xf();

        const unsigned short* lb  = smem + 49152 + (cc & 1) * 16384;
        const unsigned short* wbn = smem + 16384 + ((cc + 1) & 1) * 16384;
        const bool isRe = (cc & 3) < 2;

        // W fragments for A(cc+1), read once into registers (32 VGPRs)
        bf16x8 wfc[8];
        if (cc < 7) {
            #pragma unroll
            for (int ks = 0; ks < 8; ++ks)
                wfc[ks] = ldr(wbn, wn * 32 + l31, 2 * ks + hl);
        }

        // ---- interleaved: B(cc) t0-3 | A(cc+1) m2 0,1 | B t4-7 | A m2 2,3
        BT(0, lb, isRe); BT(1, lb, isRe); BT(2, lb, isRe); BT(3, lb, isRe);
        if (cc < 7) {
            #pragma unroll
            for (int m2 = 0; m2 < 2; ++m2) {
                f32x16 acc;
                #pragma unroll
                for (int e = 0; e < 16; ++e) acc[e] = 0.f;
                #pragma unroll
                for (int ks = 0; ks < 8; ++ks)
                    acc = MFMA32(xf[m2][ks], wfc[ks], acc);
                u[m2] = acc;
            }
        }
        BT(4, lb, isRe); BT(5, lb, isRe); BT(6, lb, isRe); BT(7, lb, isRe);
        if (cc < 7) {
            #pragma unroll
            for (int m2 = 2; m2 < 4; ++m2) {
                f32x16 acc;
                #pragma unroll
                for (int e = 0; e < 16; ++e) acc[e] = 0.f;
                #pragma unroll
                for (int ks = 0; ks < 8; ++ks)
                    acc = MFMA32(xf[m2][ks], wfc[ks], acc);
                u[m2] = acc;
            }
        }
    }

    // ---- epilogue: direct interleaved (re,im) stores, no reduction ----
    float2* o2 = (float2*)out;
    #pragma unroll
    for (int mt = 0; mt < 4; ++mt)
        #pragma unroll
        for (int j = 0; j < 16; ++j) {
            const int row = mt * 32 + (j & 3) + 8 * (j >> 2) + 4 * hl;
            float2 v;
            v.x = yre[mt][j];
            v.y = yim[mt][j];
            o2[(size_t)(b * 1024 + p * 128 + row) * 1024
               + q * 128 + wn * 32 + l31] = v;
        }
}

extern "C" void kernel_launch(void* const* d_in, const int* in_sizes, int n_in,
                              void* d_out, int out_size, void* d_ws, size_t ws_size,
                              hipStream_t stream) {
    const float* x  = (const float*)d_in[0];
    const int* perm = (const int*)d_in[1];
    unsigned short* htp = (unsigned short*)d_ws;   // 2 MB

    hipLaunchKernelGGL(prep_h, dim3(256), dim3(256), 0, stream,
        (const float*)d_in[2], (const float*)d_in[3], (const float*)d_in[4],
        (const float*)d_in[5], (const float*)d_in[6], (const float*)d_in[7],
        (const float*)d_in[8], (const float*)d_in[9], htp);
    hipLaunchKernelGGL(bilin_main, dim3(256), dim3(256), 0, stream,
        x, perm, htp, (float*)d_out);
}

// Round 13
// 38.185 us; speedup vs baseline: 1.3336x; 1.3336x over previous
//
#include <hip/hip_runtime.h>
#include <hip/hip_bf16.h>
#include <stdint.h>

typedef __attribute__((ext_vector_type(8))) short bf16x8;
typedef __attribute__((ext_vector_type(4))) float f32x4;
typedef __attribute__((ext_vector_type(16))) float f32x16;

#define MFMA32(a, b, c) __builtin_amdgcn_mfma_f32_32x32x16_bf16((a), (b), (c), 0, 0, 0)

__device__ __forceinline__ unsigned short f2bf_rn(float f) {
    union { __bf16 b; unsigned short u; } v;
    v.b = (__bf16)f;
    return v.u;
}

// pack 2 floats -> 2 bf16 in a uint (compiler fuses to v_cvt_pk_bf16_f32)
__device__ __forceinline__ unsigned int pk2(float lo, float hi) {
    union { unsigned short s[2]; unsigned int u; } r;
    r.s[0] = f2bf_rn(lo); r.s[1] = f2bf_rn(hi);
    return r.u;
}

__device__ __forceinline__ void gload_lds16(const void* g, void* l) {
    __builtin_amdgcn_global_load_lds(
        (const __attribute__((address_space(1))) void*)g,
        (__attribute__((address_space(3))) void*)l, 16, 0, 0);
}

// ---------------------------------------------------------------------------
// prep_h: transpose each 128x128 fp32 block of the 8 H tensors to bf16.
//   ht[j][blk][k][r] = h_j[blk][r][k]
// 256 WGs = jblk(64) x k-quarter(4).
// ---------------------------------------------------------------------------
__global__ __launch_bounds__(256) void prep_h(
    const float* __restrict__ h0, const float* __restrict__ h1,
    const float* __restrict__ h2, const float* __restrict__ h3,
    const float* __restrict__ h4, const float* __restrict__ h5,
    const float* __restrict__ h6, const float* __restrict__ h7,
    unsigned short* __restrict__ ht)
{
    const float* hmap[8] = {h0, h1, h2, h3, h4, h5, h6, h7};
    const int wg = blockIdx.x;            // 256 = jblk(64) x quarter(4)
    const int jblk = wg >> 2, qt = wg & 3;
    const float* src = hmap[jblk >> 3] + (jblk & 7) * 16384;
    unsigned short* dst = ht + jblk * 16384;
    __shared__ unsigned short tile[32 * 129];
    const int t = threadIdx.x;
    #pragma unroll
    for (int i = 0; i < 16; ++i) {
        int idx = t + 256 * i;            // 4096 = r(128) x kk(32)
        int r = idx >> 5, kk = idx & 31;
        tile[kk * 129 + r] = f2bf_rn(src[r * 128 + qt * 32 + kk]);
    }
    __syncthreads();
    #pragma unroll
    for (int i = 0; i < 16; ++i) {
        int idx = t + 256 * i;            // 4096 = k(32) x r(128)
        int k = idx >> 7, r = idx & 127;
        dst[(qt * 32 + k) * 128 + r] = tile[k * 129 + r];
    }
}

// ---------------------------------------------------------------------------
// bilin_main: 256 WGs = (b,p,q), q = bid&7 (XCD-locked). 256 threads =
// 4 waves, wave wn owns output cols wn*32..+32, full K=128. 32x32x16 MFMA.
// R11 structure (best verified):  both X planes resident in LDS, xf in
// REGISTERS per g; W double-buffered, Lt single-buffered, MID/END barriers.
// R13 change (R12 post-mortem: NO cross-barrier accumulator state): batch
// independent ops inside each phase —
//   stage A: preload all 8 wfr, then the 32-MFMA block;
//   stage B: precompute ALL 8 B-frags (32 cvt_pk + 16 bpermute overlap
//   once, not 8x on the chain), then 8x4 MFMA grid with lfr streamed via
//   1-step-lookahead ping-pong (all indices static).
// LDS = Xre 32K | Xim 32K | W dbuf 64K | Lt 32K = 160 KB exact.
// Regs: y 128 + xf 128 + ufu 32 + lfr 32 + wfr 32 ~= 390 peak (<450).
// LDS swizzle: 16B chunk ch of row at LDS[row][ch] = G[row][ch ^ (row&15)].
// ---------------------------------------------------------------------------
__global__ __launch_bounds__(256, 1) void bilin_main(
    const float* __restrict__ x, const int* __restrict__ perm,
    const unsigned short* __restrict__ ht, float* __restrict__ out)
{
    const int wg = blockIdx.x;
    const int q = wg & 7, p = (wg >> 3) & 7, b = wg >> 6;
    const int tid = threadIdx.x;
    const int lane = tid & 63, wn = tid >> 6;      // 4 waves
    const int l31 = lane & 31, hl = lane >> 5;

    __shared__ __align__(16) unsigned short smem[81920];   // 160 KB
    unsigned short* xre_lds = smem;                        // 32 KB
    unsigned short* xim_lds = smem + 16384;                // 32 KB
    // W[par] = smem + 32768 + par*16384 (64 KB)
    unsigned short* llds = smem + 65536;                   // 32 KB

    constexpr int cseq[8]  = {0, 1, 6, 7, 2, 3, 4, 5};
    constexpr int rperm[8] = {0, 1, 3, 2, 4, 5, 7, 6};

    // ---- staging helpers (gload_lds: wave-uniform LDS base + lane*16) ----
    const int wubase = tid & ~63;
    auto stage_h = [&](unsigned short* dst, int blk) {
        const unsigned short* src = ht + blk * 16384;
        #pragma unroll
        for (int r = 0; r < 8; ++r) {
            const int idx = r * 256 + tid;          // 16B chunk 0..2047
            const int row = idx >> 4, cin = idx & 15;
            gload_lds16(src + row * 128 + ((cin ^ (row & 15)) << 3),
                        dst + ((r * 256 + wubase) << 3));
        }
    };

    // swizzled LDS fragment read: row in [0,128), chunk in [0,16)
    auto ldr = [&](const unsigned short* base, int row, int ch) -> bf16x8 {
        return *(const bf16x8*)(base + row * 128 + ((ch ^ (row & 15)) << 3));
    };

    // fused prep_x: fp32 read ONCE -> convert -> both swizzled LDS planes
    auto stage_x_both = [&]() {
        #pragma unroll
        for (int i = 0; i < 8; ++i) {
            const int idx = i * 256 + tid;
            const int row = idx >> 4, cin = idx & 15;
            const int n1 = perm[2 * p + (row >> 6)];
            const int n2 = perm[2 * q + (cin >> 3)];
            const int r1 = row & 63, r2 = (cin & 7) * 8;
            const float* sp = x + ((size_t)((b * 16 + n1) * 64 + r1) * 1024
                                   + n2 * 64 + r2) * 2;
            float4 v0 = *(const float4*)(sp);
            float4 v1 = *(const float4*)(sp + 4);
            float4 v2 = *(const float4*)(sp + 8);
            float4 v3 = *(const float4*)(sp + 12);
            bf16x8 re, im;
            re[0] = (short)f2bf_rn(v0.x); re[1] = (short)f2bf_rn(v0.z);
            re[2] = (short)f2bf_rn(v1.x); re[3] = (short)f2bf_rn(v1.z);
            re[4] = (short)f2bf_rn(v2.x); re[5] = (short)f2bf_rn(v2.z);
            re[6] = (short)f2bf_rn(v3.x); re[7] = (short)f2bf_rn(v3.z);
            im[0] = (short)f2bf_rn(v0.y); im[1] = (short)f2bf_rn(v0.w);
            im[2] = (short)f2bf_rn(v1.y); im[3] = (short)f2bf_rn(v1.w);
            im[4] = (short)f2bf_rn(v2.y); im[5] = (short)f2bf_rn(v2.w);
            im[6] = (short)f2bf_rn(v3.y); im[7] = (short)f2bf_rn(v3.w);
            const int woff = row * 128 + ((cin ^ (row & 15)) << 3);
            *(bf16x8*)(xre_lds + woff) = re;
            *(bf16x8*)(xim_lds + woff) = im;
        }
    };

    // X fragments for the whole 128-row tile, in registers (128 VGPRs)
    bf16x8 xf[4][8];
    auto load_xf = [&](const unsigned short* plane) {
        #pragma unroll
        for (int m2 = 0; m2 < 4; ++m2)
            #pragma unroll
            for (int ks = 0; ks < 8; ++ks)
                xf[m2][ks] = ldr(plane, m2 * 32 + l31, 2 * ks + hl);
    };

    // ---- prologue ----
    stage_h(smem + 32768, rperm[0] * 8 + q);   // W(0)
    stage_h(llds, 0 * 8 + p);                  // Lt(0)
    stage_x_both();
    __syncthreads();          // drains gloads, orders X plane writes
    load_xf(xre_lds);

    f32x16 yre[4], yim[4];
    #pragma unroll
    for (int i = 0; i < 4; ++i) {
        #pragma unroll
        for (int e = 0; e < 16; ++e) { yre[i][e] = 0.f; yim[i][e] = 0.f; }
    }

    #pragma unroll
    for (int cc = 0; cc < 8; ++cc) {
        const unsigned short* wb = smem + 32768 + (cc & 1) * 16384;

        // issue next W (opposite parity, last read in stage A(cc-1)): drains
        // at this c's END barrier
        if (cc < 7)
            stage_h(smem + 32768 + ((cc + 1) & 1) * 16384,
                    rperm[cseq[cc + 1]] * 8 + q);

        // g switch: planes are static after prologue — plain reload
        if (cc == 4) load_xf(xim_lds);

        // ---- stage A: preload all 8 wfr (independent), then 32 MFMAs
        bf16x8 wfr[8];
        #pragma unroll
        for (int ks = 0; ks < 8; ++ks)
            wfr[ks] = ldr(wb, wn * 32 + l31, 2 * ks + hl);
        f32x16 u[4];
        #pragma unroll
        for (int m2 = 0; m2 < 4; ++m2)
            #pragma unroll
            for (int e = 0; e < 16; ++e) u[m2][e] = 0.f;
        #pragma unroll
        for (int ks = 0; ks < 8; ++ks)
            #pragma unroll
            for (int m2 = 0; m2 < 4; ++m2)
                u[m2] = MFMA32(xf[m2][ks], wfr[ks], u[m2]);

        __syncthreads();   // MID: drains Lt(c) (issued at END of cc-1)

        // ---- stage B: build ALL 8 B-frags first (shfl latencies overlap
        // once), then the 8x4 MFMA grid with lfr ping-pong lookahead.
        union UF { unsigned int d[4]; bf16x8 v; };
        UF ufu[8];
        #pragma unroll
        for (int t = 0; t < 8; ++t) {
            const int f = t >> 1, qa = (t & 1) * 2, qb = qa + 1;
            unsigned int lo0 = pk2(u[f][4 * qa + 0], u[f][4 * qa + 1]);
            unsigned int lo1 = pk2(u[f][4 * qa + 2], u[f][4 * qa + 3]);
            unsigned int hi0 = pk2(u[f][4 * qb + 0], u[f][4 * qb + 1]);
            unsigned int hi1 = pk2(u[f][4 * qb + 2], u[f][4 * qb + 3]);
            unsigned int send0 = hl ? lo0 : hi0;
            unsigned int send1 = hl ? lo1 : hi1;
            unsigned int sx0 = (unsigned int)__shfl_xor((int)send0, 32);
            unsigned int sx1 = (unsigned int)__shfl_xor((int)send1, 32);
            ufu[t].d[0] = hl ? sx0 : lo0;
            ufu[t].d[1] = hl ? sx1 : lo1;
            ufu[t].d[2] = hl ? hi0 : sx0;
            ufu[t].d[3] = hl ? hi1 : sx1;
        }
        const bool isRe = (cc & 3) < 2;
        bf16x8 lcur[4], lnxt[4];
        #pragma unroll
        for (int mt = 0; mt < 4; ++mt)
            lcur[mt] = ldr(llds, mt * 32 + l31, hl);          // t=0
        #pragma unroll
        for (int t = 0; t < 8; ++t) {
            if (t < 7) {
                #pragma unroll
                for (int mt = 0; mt < 4; ++mt)
                    lnxt[mt] = ldr(llds, mt * 32 + l31, 2 * (t + 1) + hl);
            }
            #pragma unroll
            for (int mt = 0; mt < 4; ++mt) {
                if (isRe) yre[mt] = MFMA32(lcur[mt], ufu[t].v, yre[mt]);
                else      yim[mt] = MFMA32(lcur[mt], ufu[t].v, yim[mt]);
            }
            #pragma unroll
            for (int mt = 0; mt < 4; ++mt) lcur[mt] = lnxt[mt];
        }

        __syncthreads();   // END: all waves done with llds; drains W(c+1)
        if (cc < 7)
            stage_h(llds, cseq[cc + 1] * 8 + p);   // drains at MID(cc+1)
    }

    // ---- epilogue: direct interleaved (re,im) stores, no reduction ----
    float2* o2 = (float2*)out;
    #pragma unroll
    for (int mt = 0; mt < 4; ++mt)
        #pragma unroll
        for (int j = 0; j < 16; ++j) {
            const int row = mt * 32 + (j & 3) + 8 * (j >> 2) + 4 * hl;
            float2 v;
            v.x = yre[mt][j];
            v.y = yim[mt][j];
            o2[(size_t)(b * 1024 + p * 128 + row) * 1024
               + q * 128 + wn * 32 + l31] = v;
        }
}

extern "C" void kernel_launch(void* const* d_in, const int* in_sizes, int n_in,
                              void* d_out, int out_size, void* d_ws, size_t ws_size,
                              hipStream_t stream) {
    const float* x  = (const float*)d_in[0];
    const int* perm = (const int*)d_in[1];
    unsigned short* htp = (unsigned short*)d_ws;   // 2 MB

    hipLaunchKernelGGL(prep_h, dim3(256), dim3(256), 0, stream,
        (const float*)d_in[2], (const float*)d_in[3], (const float*)d_in[4],
        (const float*)d_in[5], (const float*)d_in[6], (const float*)d_in[7],
        (const float*)d_in[8], (const float*)d_in[9], htp);
    hipLaunchKernelGGL(bilin_main, dim3(256), dim3(256), 0, stream,
        x, perm, htp, (float*)d_out);
}